// Round 2
// baseline (857.986 us; speedup 1.0000x reference)
//
#include <hip/hip_runtime.h>

#define N_NODES 100000
#define N_EDGES 1600000
#define N_GRAPHS 1024
#define BN_EPS 1e-5f
#define NSCAN 98  // ceil(100000/1024)

// ================= CSR build =================
__global__ __launch_bounds__(256) void hist_kernel(const int* __restrict__ dst,
                                                   int* __restrict__ cnt) {
    int e = blockIdx.x * 256 + threadIdx.x;
    if (e < N_EDGES) atomicAdd(&cnt[dst[e]], 1);
}

// per-block exclusive scan over 1024 counts (256 threads x 4)
__global__ __launch_bounds__(256) void scan_blocks(const int* __restrict__ cnt,
                                                   int* __restrict__ rowptr,
                                                   int* __restrict__ bsum) {
    __shared__ int ts[256];
    int base = blockIdx.x * 1024 + threadIdx.x * 4;
    int c[4];
#pragma unroll
    for (int i = 0; i < 4; i++) {
        int idx = base + i;
        c[i] = (idx < N_NODES) ? cnt[idx] : 0;
    }
    int s = c[0] + c[1] + c[2] + c[3];
    ts[threadIdx.x] = s;
    __syncthreads();
    for (int off = 1; off < 256; off <<= 1) {
        int v = (threadIdx.x >= off) ? ts[threadIdx.x - off] : 0;
        __syncthreads();
        ts[threadIdx.x] += v;
        __syncthreads();
    }
    int run = ts[threadIdx.x] - s;  // exclusive
#pragma unroll
    for (int i = 0; i < 4; i++) {
        int idx = base + i;
        if (idx < N_NODES) rowptr[idx] = run;
        run += c[i];
    }
    if (threadIdx.x == 255) bsum[blockIdx.x] = ts[255];
}

__global__ void scan_sums(int* bsum) {
    if (threadIdx.x == 0) {
        int run = 0;
        for (int i = 0; i < NSCAN; i++) {
            int v = bsum[i];
            bsum[i] = run;
            run += v;
        }
    }
}

__global__ __launch_bounds__(256) void scan_apply(int* __restrict__ rowptr,
                                                  const int* __restrict__ bsum,
                                                  int* __restrict__ cursor) {
    int i = blockIdx.x * 256 + threadIdx.x;
    if (i < N_NODES) {
        int v = rowptr[i] + bsum[i >> 10];
        rowptr[i] = v;
        cursor[i] = v;
    }
}

// elist[pos] = src of each edge, bucketed by dst
__global__ __launch_bounds__(256) void scatter_kernel(const int* __restrict__ src,
                                                      const int* __restrict__ dst,
                                                      int* __restrict__ cursor,
                                                      int* __restrict__ elist) {
    int e = blockIdx.x * 256 + threadIdx.x;
    if (e < N_EDGES) {
        int p = atomicAdd(&cursor[dst[e]], 1);
        elist[p] = src[e];
    }
}

// ================= aggregation by gather (no fp32 atomics) =================
// 8 lanes per node, one feature each (f<7); includes self term
__global__ __launch_bounds__(256) void gather7(const float* __restrict__ x,
                                               const int* __restrict__ rowptr,
                                               const int* __restrict__ cnt,
                                               const int* __restrict__ elist,
                                               float* __restrict__ agg) {
    int t = blockIdx.x * 256 + threadIdx.x;
    int n = t >> 3, f = t & 7;
    if (n >= N_NODES || f >= 7) return;
    int start = rowptr[n], k = cnt[n];
    float a = x[(size_t)n * 7 + f];
    for (int i = 0; i < k; i++) {
        int s = elist[start + i];
        a += x[(size_t)s * 7 + f];
    }
    agg[(size_t)n * 7 + f] = a;
}

// 16 lanes per node, float4 each; includes self term
__global__ __launch_bounds__(256) void gather64(const float* __restrict__ h,
                                                const int* __restrict__ rowptr,
                                                const int* __restrict__ cnt,
                                                const int* __restrict__ elist,
                                                float* __restrict__ agg) {
    int t = blockIdx.x * 256 + threadIdx.x;
    int n = t >> 4, c = t & 15;
    if (n >= N_NODES) return;
    int start = rowptr[n], k = cnt[n];
    const float4* h4 = (const float4*)h;
    float4 a = h4[(size_t)n * 16 + c];
    for (int i = 0; i < k; i++) {
        int s = elist[start + i];
        float4 v = h4[(size_t)s * 16 + c];
        a.x += v.x;
        a.y += v.y;
        a.z += v.z;
        a.w += v.w;
    }
    ((float4*)agg)[(size_t)n * 16 + c] = a;
}

// ================= MLP: h2 = relu(agg@w1+b1)@w2+b2 =================
// one row per thread; weights are wave-uniform -> scalar (s_load) broadcast
template <int DIN>
__global__ __launch_bounds__(256) void mlp_kernel(const float* __restrict__ agg,
                                                  const float* __restrict__ w1,
                                                  const float* __restrict__ b1,
                                                  const float* __restrict__ w2,
                                                  const float* __restrict__ b2,
                                                  float* __restrict__ h2out) {
    int row = blockIdx.x * 256 + threadIdx.x;
    if (row >= N_NODES) return;
    const float* xr = agg + (size_t)row * DIN;

    float h1[64];
#pragma unroll
    for (int j = 0; j < 64; j++) h1[j] = b1[j];

    if constexpr (DIN == 7) {
#pragma unroll
        for (int k = 0; k < 7; k++) {
            float xv = xr[k];
#pragma unroll
            for (int j = 0; j < 64; j++) h1[j] = fmaf(xv, w1[k * 64 + j], h1[j]);
        }
    } else {
        const float4* xp = (const float4*)xr;
        for (int kk = 0; kk < DIN / 4; kk++) {
            float4 xv = xp[kk];
            const float* w = w1 + kk * 4 * 64;
#pragma unroll
            for (int j = 0; j < 64; j++) h1[j] = fmaf(xv.x, w[j], h1[j]);
#pragma unroll
            for (int j = 0; j < 64; j++) h1[j] = fmaf(xv.y, w[64 + j], h1[j]);
#pragma unroll
            for (int j = 0; j < 64; j++) h1[j] = fmaf(xv.z, w[128 + j], h1[j]);
#pragma unroll
            for (int j = 0; j < 64; j++) h1[j] = fmaf(xv.w, w[192 + j], h1[j]);
        }
    }
#pragma unroll
    for (int j = 0; j < 64; j++) h1[j] = fmaxf(h1[j], 0.0f);

    // second matmul: 4 columns at a time, float4 store
    for (int j4 = 0; j4 < 16; j4++) {
        float4 o;
        float* ov = (float*)&o;
#pragma unroll
        for (int jj = 0; jj < 4; jj++) {
            int j = j4 * 4 + jj;
            float a = b2[j];
#pragma unroll
            for (int k = 0; k < 64; k++) a = fmaf(h1[k], w2[k * 64 + j], a);
            ov[jj] = a;
        }
        ((float4*)(h2out + (size_t)row * 64))[j4] = o;
    }
}

// ================= BN stats: per-feature sum / sumsq (fp64 accumulators) =================
__global__ __launch_bounds__(256) void bn_stats(const float* __restrict__ h2,
                                                double* __restrict__ acc) {
    long base = (long)blockIdx.x * 256 * 64;
    long end = base + 256L * 64;
    long lim = (long)N_NODES * 64;
    if (end > lim) end = lim;
    float s = 0.f, sq = 0.f;
    for (long i = base + threadIdx.x; i < end; i += 256) {
        float v = h2[i];
        s += v;
        sq += v * v;
    }
    __shared__ float ls[256], lq[256];
    ls[threadIdx.x] = s;
    lq[threadIdx.x] = sq;
    __syncthreads();
    if (threadIdx.x < 64) {
        float S = ls[threadIdx.x] + ls[threadIdx.x + 64] + ls[threadIdx.x + 128] + ls[threadIdx.x + 192];
        float Q = lq[threadIdx.x] + lq[threadIdx.x + 64] + lq[threadIdx.x + 128] + lq[threadIdx.x + 192];
        atomicAdd(&acc[threadIdx.x], (double)S);
        atomicAdd(&acc[64 + threadIdx.x], (double)Q);
    }
}

__global__ void bn_finalize(const double* __restrict__ acc, const float* __restrict__ gamma,
                            const float* __restrict__ beta, float* __restrict__ ss) {
    int j = threadIdx.x;
    if (j >= 64) return;
    double inv = 1.0 / (double)N_NODES;
    double mean = acc[j] * inv;
    double var = acc[64 + j] * inv - mean * mean;
    float scale = gamma[j] / sqrtf((float)var + BN_EPS);
    ss[j] = scale;
    ss[64 + j] = beta[j] - (float)mean * scale;
}

// ================= BN apply + relu =================
__global__ __launch_bounds__(256) void bn_relu(const float* __restrict__ h2,
                                               const float* __restrict__ ss,
                                               float* __restrict__ hout) {
    int t = blockIdx.x * 256 + threadIdx.x;
    if (t >= N_NODES * 16) return;
    int c = t & 15;
    float4 v = ((const float4*)h2)[t];
    float4 sc = ((const float4*)ss)[c];
    float4 sh = ((const float4*)(ss + 64))[c];
    float4 o;
    o.x = fmaxf(fmaf(v.x, sc.x, sh.x), 0.0f);
    o.y = fmaxf(fmaf(v.y, sc.y, sh.y), 0.0f);
    o.z = fmaxf(fmaf(v.z, sc.z, sh.z), 0.0f);
    o.w = fmaxf(fmaf(v.w, sc.w, sh.w), 0.0f);
    ((float4*)hout)[t] = o;
}

// ================= last layer: BN apply + relu + mean-pool atomics =================
__global__ __launch_bounds__(256) void bn_relu_pool(const float* __restrict__ h2,
                                                    const float* __restrict__ ss,
                                                    const int* __restrict__ batch,
                                                    float* __restrict__ pooled,
                                                    float* __restrict__ counts) {
    int t = blockIdx.x * 256 + threadIdx.x;
    if (t >= N_NODES * 16) return;
    int row = t >> 4, c = t & 15;
    float4 v = ((const float4*)h2)[t];
    float4 sc = ((const float4*)ss)[c];
    float4 sh = ((const float4*)(ss + 64))[c];
    float4 o;
    o.x = fmaxf(fmaf(v.x, sc.x, sh.x), 0.0f);
    o.y = fmaxf(fmaf(v.y, sc.y, sh.y), 0.0f);
    o.z = fmaxf(fmaf(v.z, sc.z, sh.z), 0.0f);
    o.w = fmaxf(fmaf(v.w, sc.w, sh.w), 0.0f);
    int g = batch[row];
    float* pp = pooled + (size_t)g * 64 + (size_t)c * 4;
    atomicAdd(pp + 0, o.x);
    atomicAdd(pp + 1, o.y);
    atomicAdd(pp + 2, o.z);
    atomicAdd(pp + 3, o.w);
    if (c == 0) atomicAdd(&counts[g], 1.0f);
}

// ================= final: proj + L2 normalize; one wave per graph =================
__global__ __launch_bounds__(256) void final_proj(const float* __restrict__ pooled,
                                                  const float* __restrict__ counts,
                                                  const float* __restrict__ pw,
                                                  const float* __restrict__ pb,
                                                  float* __restrict__ out) {
    __shared__ float sw[64 * 64];
    for (int i = threadIdx.x; i < 4096; i += 256) sw[i] = pw[i];
    __syncthreads();
    int g = blockIdx.x * 4 + (threadIdx.x >> 6);
    int j = threadIdx.x & 63;
    if (g >= N_GRAPHS) return;
    float inv = 1.0f / fmaxf(counts[g], 1.0f);
    float a = pb[j];
#pragma unroll
    for (int k = 0; k < 64; k++) a = fmaf(pooled[(size_t)g * 64 + k] * inv, sw[k * 64 + j], a);
    float ss2 = a * a;
#pragma unroll
    for (int off = 1; off < 64; off <<= 1) ss2 += __shfl_xor(ss2, off);
    out[(size_t)g * 64 + j] = a / fmaxf(sqrtf(ss2), 1e-12f);
}

extern "C" void kernel_launch(void* const* d_in, const int* in_sizes, int n_in,
                              void* d_out, int out_size, void* d_ws, size_t ws_size,
                              hipStream_t stream) {
    const float* x = (const float*)d_in[0];
    const int* eidx = (const int*)d_in[1];
    const int* batch = (const int*)d_in[2];
    const int* src = eidx;
    const int* dst = eidx + N_EDGES;
    const float* W1[3] = {(const float*)d_in[3], (const float*)d_in[9], (const float*)d_in[15]};
    const float* B1[3] = {(const float*)d_in[4], (const float*)d_in[10], (const float*)d_in[16]};
    const float* W2[3] = {(const float*)d_in[5], (const float*)d_in[11], (const float*)d_in[17]};
    const float* B2[3] = {(const float*)d_in[6], (const float*)d_in[12], (const float*)d_in[18]};
    const float* GM[3] = {(const float*)d_in[7], (const float*)d_in[13], (const float*)d_in[19]};
    const float* BT[3] = {(const float*)d_in[8], (const float*)d_in[14], (const float*)d_in[20]};
    const float* PW = (const float*)d_in[21];
    const float* PB = (const float*)d_in[22];
    float* out = (float*)d_out;

    char* ws = (char*)d_ws;
    size_t off = 0;
    auto alloc = [&](size_t bytes) -> void* {
        void* p = ws + off;
        off += (bytes + 255) & ~(size_t)255;
        return p;
    };
    float* A   = (float*)alloc((size_t)N_NODES * 64 * 4);  // h2 buffer
    float* Bb  = (float*)alloc((size_t)N_NODES * 64 * 4);  // h buffer
    float* C   = (float*)alloc((size_t)N_NODES * 64 * 4);  // agg buffer
    float* agg0 = (float*)alloc((size_t)N_NODES * 7 * 4);
    int* cnt    = (int*)alloc((size_t)N_NODES * 4);
    int* rowptr = (int*)alloc((size_t)N_NODES * 4);
    int* cursor = (int*)alloc((size_t)N_NODES * 4);
    int* bsum   = (int*)alloc(NSCAN * 4);
    int* elist  = (int*)alloc((size_t)N_EDGES * 4);
    double* acc = (double*)alloc(3 * 128 * sizeof(double));
    float* ssbuf  = (float*)alloc(128 * 4);
    float* pooled = (float*)alloc((size_t)N_GRAPHS * 64 * 4);
    float* counts = (float*)alloc((size_t)N_GRAPHS * 4);

    hipMemsetAsync(cnt, 0, (size_t)N_NODES * 4, stream);
    hipMemsetAsync(acc, 0, 3 * 128 * sizeof(double), stream);
    hipMemsetAsync(pooled, 0, (size_t)N_GRAPHS * 64 * 4, stream);
    hipMemsetAsync(counts, 0, (size_t)N_GRAPHS * 4, stream);

    const int edge_grid = (N_EDGES + 255) / 256;       // 6250
    const int row_grid = (N_NODES + 255) / 256;        // 391
    const int vec_grid = (N_NODES * 16 + 255) / 256;   // 6250
    const int g7_grid = (N_NODES * 8 + 255) / 256;     // 3125

    // ---- CSR build (once, reused by all 3 layers) ----
    hist_kernel<<<edge_grid, 256, 0, stream>>>(dst, cnt);
    scan_blocks<<<NSCAN, 256, 0, stream>>>(cnt, rowptr, bsum);
    scan_sums<<<1, 64, 0, stream>>>(bsum);
    scan_apply<<<row_grid, 256, 0, stream>>>(rowptr, bsum, cursor);
    scatter_kernel<<<edge_grid, 256, 0, stream>>>(src, dst, cursor, elist);

    // ---- layer 0 ----
    gather7<<<g7_grid, 256, 0, stream>>>(x, rowptr, cnt, elist, agg0);
    mlp_kernel<7><<<row_grid, 256, 0, stream>>>(agg0, W1[0], B1[0], W2[0], B2[0], A);
    bn_stats<<<row_grid, 256, 0, stream>>>(A, acc);
    bn_finalize<<<1, 64, 0, stream>>>(acc, GM[0], BT[0], ssbuf);
    bn_relu<<<vec_grid, 256, 0, stream>>>(A, ssbuf, Bb);

    // ---- layer 1 ----
    gather64<<<vec_grid, 256, 0, stream>>>(Bb, rowptr, cnt, elist, C);
    mlp_kernel<64><<<row_grid, 256, 0, stream>>>(C, W1[1], B1[1], W2[1], B2[1], A);
    bn_stats<<<row_grid, 256, 0, stream>>>(A, acc + 128);
    bn_finalize<<<1, 64, 0, stream>>>(acc + 128, GM[1], BT[1], ssbuf);
    bn_relu<<<vec_grid, 256, 0, stream>>>(A, ssbuf, Bb);

    // ---- layer 2 ----
    gather64<<<vec_grid, 256, 0, stream>>>(Bb, rowptr, cnt, elist, C);
    mlp_kernel<64><<<row_grid, 256, 0, stream>>>(C, W1[2], B1[2], W2[2], B2[2], A);
    bn_stats<<<row_grid, 256, 0, stream>>>(A, acc + 256);
    bn_finalize<<<1, 64, 0, stream>>>(acc + 256, GM[2], BT[2], ssbuf);
    bn_relu_pool<<<vec_grid, 256, 0, stream>>>(A, ssbuf, batch, pooled, counts);

    // ---- readout ----
    final_proj<<<N_GRAPHS / 4, 256, 0, stream>>>(pooled, counts, PW, PB, out);
}

// Round 5
// 752.444 us; speedup vs baseline: 1.1403x; 1.1403x over previous
//
#include <hip/hip_runtime.h>

#define N_NODES 100000
#define N_EDGES 1600000
#define N_GRAPHS 1024
#define BN_EPS 1e-5f
#define NSCAN 98  // ceil(100000/1024)

// ================= CSR build (dst -> list of src) =================
__global__ __launch_bounds__(256) void hist_kernel(const int* __restrict__ dst,
                                                   int* __restrict__ cnt) {
    int e = blockIdx.x * 256 + threadIdx.x;
    if (e < N_EDGES) atomicAdd(&cnt[dst[e]], 1);
}

// per-block exclusive scan over 1024 counts (256 threads x 4)
__global__ __launch_bounds__(256) void scan_blocks(const int* __restrict__ cnt,
                                                   int* __restrict__ rowptr,
                                                   int* __restrict__ bsum) {
    __shared__ int ts[256];
    int base = blockIdx.x * 1024 + threadIdx.x * 4;
    int c[4];
#pragma unroll
    for (int i = 0; i < 4; i++) {
        int idx = base + i;
        c[i] = (idx < N_NODES) ? cnt[idx] : 0;
    }
    int s = c[0] + c[1] + c[2] + c[3];
    ts[threadIdx.x] = s;
    __syncthreads();
    for (int off = 1; off < 256; off <<= 1) {
        int v = (threadIdx.x >= off) ? ts[threadIdx.x - off] : 0;
        __syncthreads();
        ts[threadIdx.x] += v;
        __syncthreads();
    }
    int run = ts[threadIdx.x] - s;  // exclusive
#pragma unroll
    for (int i = 0; i < 4; i++) {
        int idx = base + i;
        if (idx < N_NODES) rowptr[idx] = run;
        run += c[i];
    }
    if (threadIdx.x == 255) bsum[blockIdx.x] = ts[255];
}

__global__ void scan_sums(int* bsum) {
    if (threadIdx.x == 0) {
        int run = 0;
        for (int i = 0; i < NSCAN; i++) {
            int v = bsum[i];
            bsum[i] = run;
            run += v;
        }
    }
}

__global__ __launch_bounds__(256) void scan_apply(int* __restrict__ rowptr,
                                                  const int* __restrict__ bsum,
                                                  int* __restrict__ cursor) {
    int i = blockIdx.x * 256 + threadIdx.x;
    if (i < N_NODES) {
        int v = rowptr[i] + bsum[i >> 10];
        rowptr[i] = v;
        cursor[i] = v;
    }
}

// elist[pos] = src of each edge, bucketed by dst
__global__ __launch_bounds__(256) void scatter_kernel(const int* __restrict__ src,
                                                      const int* __restrict__ dst,
                                                      int* __restrict__ cursor,
                                                      int* __restrict__ elist) {
    int e = blockIdx.x * 256 + threadIdx.x;
    if (e < N_EDGES) {
        int p = atomicAdd(&cursor[dst[e]], 1);
        elist[p] = src[e];
    }
}

// ================= graph CSR from sorted batch =================
__global__ __launch_bounds__(256) void ghist_kernel(const int* __restrict__ batch,
                                                    int* __restrict__ gcnt) {
    int i = blockIdx.x * 256 + threadIdx.x;
    if (i < N_NODES) atomicAdd(&gcnt[batch[i]], 1);
}

// one block; exclusive scan over 1024 graph counts -> grow[0..1024]
__global__ __launch_bounds__(256) void gscan_kernel(const int* __restrict__ gcnt,
                                                    int* __restrict__ grow) {
    __shared__ int ts[256];
    int base = threadIdx.x * 4;
    int c[4];
#pragma unroll
    for (int i = 0; i < 4; i++) c[i] = gcnt[base + i];
    int s = c[0] + c[1] + c[2] + c[3];
    ts[threadIdx.x] = s;
    __syncthreads();
    for (int off = 1; off < 256; off <<= 1) {
        int v = (threadIdx.x >= off) ? ts[threadIdx.x - off] : 0;
        __syncthreads();
        ts[threadIdx.x] += v;
        __syncthreads();
    }
    int run = ts[threadIdx.x] - s;
#pragma unroll
    for (int i = 0; i < 4; i++) {
        grow[base + i] = run;
        run += c[i];
    }
    if (threadIdx.x == 255) grow[1024] = ts[255];
}

// ================= aggregation by gather (no fp32 atomics) =================
// 8 lanes per node, one feature each (f<7); includes self term
__global__ __launch_bounds__(256) void gather7(const float* __restrict__ x,
                                               const int* __restrict__ rowptr,
                                               const int* __restrict__ cnt,
                                               const int* __restrict__ elist,
                                               float* __restrict__ agg) {
    int t = blockIdx.x * 256 + threadIdx.x;
    int n = t >> 3, f = t & 7;
    if (n >= N_NODES || f >= 7) return;
    int start = rowptr[n], k = cnt[n];
    float a = x[(size_t)n * 7 + f];
    for (int i = 0; i < k; i++) {
        int s = elist[start + i];
        a += x[(size_t)s * 7 + f];
    }
    agg[(size_t)n * 7 + f] = a;
}

// 16 lanes per node, float4 each; applies BN(scale/shift)+relu to every
// gathered row on the fly (relu precedes summation), includes self term
__global__ __launch_bounds__(256) void gather64_bn(const float* __restrict__ h2,
                                                   const float* __restrict__ ss,
                                                   const int* __restrict__ rowptr,
                                                   const int* __restrict__ cnt,
                                                   const int* __restrict__ elist,
                                                   float* __restrict__ agg) {
    int t = blockIdx.x * 256 + threadIdx.x;
    int n = t >> 4, c = t & 15;
    if (n >= N_NODES) return;
    float4 sc = ((const float4*)ss)[c];
    float4 sh = ((const float4*)(ss + 64))[c];
    int start = rowptr[n], k = cnt[n];
    const float4* h4 = (const float4*)h2;
    float4 v = h4[(size_t)n * 16 + c];
    float4 a;
    a.x = fmaxf(fmaf(v.x, sc.x, sh.x), 0.0f);
    a.y = fmaxf(fmaf(v.y, sc.y, sh.y), 0.0f);
    a.z = fmaxf(fmaf(v.z, sc.z, sh.z), 0.0f);
    a.w = fmaxf(fmaf(v.w, sc.w, sh.w), 0.0f);
    for (int i = 0; i < k; i++) {
        int s = elist[start + i];
        float4 w = h4[(size_t)s * 16 + c];
        a.x += fmaxf(fmaf(w.x, sc.x, sh.x), 0.0f);
        a.y += fmaxf(fmaf(w.y, sc.y, sh.y), 0.0f);
        a.z += fmaxf(fmaf(w.z, sc.z, sh.z), 0.0f);
        a.w += fmaxf(fmaf(w.w, sc.w, sh.w), 0.0f);
    }
    ((float4*)agg)[(size_t)n * 16 + c] = a;
}

// ================= MLP: h2 = relu(agg@w1+b1)@w2+b2 =================
template <int DIN>
__global__ __launch_bounds__(256) void mlp_kernel(const float* __restrict__ agg,
                                                  const float* __restrict__ w1,
                                                  const float* __restrict__ b1,
                                                  const float* __restrict__ w2,
                                                  const float* __restrict__ b2,
                                                  float* __restrict__ h2out) {
    int row = blockIdx.x * 256 + threadIdx.x;
    if (row >= N_NODES) return;
    const float* xr = agg + (size_t)row * DIN;

    float h1[64];
#pragma unroll
    for (int j = 0; j < 64; j++) h1[j] = b1[j];

    if constexpr (DIN == 7) {
#pragma unroll
        for (int k = 0; k < 7; k++) {
            float xv = xr[k];
#pragma unroll
            for (int j = 0; j < 64; j++) h1[j] = fmaf(xv, w1[k * 64 + j], h1[j]);
        }
    } else {
        const float4* xp = (const float4*)xr;
        for (int kk = 0; kk < DIN / 4; kk++) {
            float4 xv = xp[kk];
            const float* w = w1 + kk * 4 * 64;
#pragma unroll
            for (int j = 0; j < 64; j++) h1[j] = fmaf(xv.x, w[j], h1[j]);
#pragma unroll
            for (int j = 0; j < 64; j++) h1[j] = fmaf(xv.y, w[64 + j], h1[j]);
#pragma unroll
            for (int j = 0; j < 64; j++) h1[j] = fmaf(xv.z, w[128 + j], h1[j]);
#pragma unroll
            for (int j = 0; j < 64; j++) h1[j] = fmaf(xv.w, w[192 + j], h1[j]);
        }
    }
#pragma unroll
    for (int j = 0; j < 64; j++) h1[j] = fmaxf(h1[j], 0.0f);

    for (int j4 = 0; j4 < 16; j4++) {
        float4 o;
        float* ov = (float*)&o;
#pragma unroll
        for (int jj = 0; jj < 4; jj++) {
            int j = j4 * 4 + jj;
            float a = b2[j];
#pragma unroll
            for (int k = 0; k < 64; k++) a = fmaf(h1[k], w2[k * 64 + j], a);
            ov[jj] = a;
        }
        ((float4*)(h2out + (size_t)row * 64))[j4] = o;
    }
}

// ================= BN stats: per-feature sum / sumsq (fp64 accumulators) =================
__global__ __launch_bounds__(256) void bn_stats(const float* __restrict__ h2,
                                                double* __restrict__ acc) {
    long base = (long)blockIdx.x * 256 * 64;
    long end = base + 256L * 64;
    long lim = (long)N_NODES * 64;
    if (end > lim) end = lim;
    float s = 0.f, sq = 0.f;
    for (long i = base + threadIdx.x; i < end; i += 256) {
        float v = h2[i];
        s += v;
        sq += v * v;
    }
    __shared__ float ls[256], lq[256];
    ls[threadIdx.x] = s;
    lq[threadIdx.x] = sq;
    __syncthreads();
    if (threadIdx.x < 64) {
        float S = ls[threadIdx.x] + ls[threadIdx.x + 64] + ls[threadIdx.x + 128] + ls[threadIdx.x + 192];
        float Q = lq[threadIdx.x] + lq[threadIdx.x + 64] + lq[threadIdx.x + 128] + lq[threadIdx.x + 192];
        atomicAdd(&acc[threadIdx.x], (double)S);
        atomicAdd(&acc[64 + threadIdx.x], (double)Q);
    }
}

__global__ void bn_finalize(const double* __restrict__ acc, const float* __restrict__ gamma,
                            const float* __restrict__ beta, float* __restrict__ ss) {
    int j = threadIdx.x;
    if (j >= 64) return;
    double inv = 1.0 / (double)N_NODES;
    double mean = acc[j] * inv;
    double var = acc[64 + j] * inv - mean * mean;
    float scale = gamma[j] / sqrtf((float)var + BN_EPS);
    ss[j] = scale;
    ss[64 + j] = beta[j] - (float)mean * scale;
}

// ================= pool: BN+relu+mean over each graph's nodes (no atomics) =================
// one block per graph; 16 node-groups x 16 float4-columns
__global__ __launch_bounds__(256) void pool_bn(const float* __restrict__ h2,
                                               const float* __restrict__ ss,
                                               const int* __restrict__ grow,
                                               float* __restrict__ pooled) {
    int g = blockIdx.x;
    int start = grow[g], end = grow[g + 1];
    int c = threadIdx.x & 15, grp = threadIdx.x >> 4;
    float4 sc = ((const float4*)ss)[c];
    float4 sh = ((const float4*)(ss + 64))[c];
    const float4* h4 = (const float4*)h2;
    float4 a = {0.f, 0.f, 0.f, 0.f};
    for (int n = start + grp; n < end; n += 16) {
        float4 v = h4[(size_t)n * 16 + c];
        a.x += fmaxf(fmaf(v.x, sc.x, sh.x), 0.0f);
        a.y += fmaxf(fmaf(v.y, sc.y, sh.y), 0.0f);
        a.z += fmaxf(fmaf(v.z, sc.z, sh.z), 0.0f);
        a.w += fmaxf(fmaf(v.w, sc.w, sh.w), 0.0f);
    }
    __shared__ float4 ls[256];
    ls[threadIdx.x] = a;
    __syncthreads();
    for (int off = 128; off >= 16; off >>= 1) {
        if (threadIdx.x < off) {
            float4 b = ls[threadIdx.x + off];
            ls[threadIdx.x].x += b.x;
            ls[threadIdx.x].y += b.y;
            ls[threadIdx.x].z += b.z;
            ls[threadIdx.x].w += b.w;
        }
        __syncthreads();
    }
    if (threadIdx.x < 16) {
        float inv = 1.0f / fmaxf((float)(end - start), 1.0f);
        float4 r = ls[threadIdx.x];
        r.x *= inv; r.y *= inv; r.z *= inv; r.w *= inv;
        ((float4*)pooled)[(size_t)g * 16 + threadIdx.x] = r;
    }
}

// ================= final: proj + L2 normalize; one wave per graph =================
__global__ __launch_bounds__(256) void final_proj(const float* __restrict__ pooled,
                                                  const float* __restrict__ pw,
                                                  const float* __restrict__ pb,
                                                  float* __restrict__ out) {
    __shared__ float sw[64 * 64];
    for (int i = threadIdx.x; i < 4096; i += 256) sw[i] = pw[i];
    __syncthreads();
    int g = blockIdx.x * 4 + (threadIdx.x >> 6);
    int j = threadIdx.x & 63;
    if (g >= N_GRAPHS) return;
    float a = pb[j];
#pragma unroll
    for (int k = 0; k < 64; k++) a = fmaf(pooled[(size_t)g * 64 + k], sw[k * 64 + j], a);
    float ss2 = a * a;
#pragma unroll
    for (int off = 1; off < 64; off <<= 1) ss2 += __shfl_xor(ss2, off);
    out[(size_t)g * 64 + j] = a / fmaxf(sqrtf(ss2), 1e-12f);
}

extern "C" void kernel_launch(void* const* d_in, const int* in_sizes, int n_in,
                              void* d_out, int out_size, void* d_ws, size_t ws_size,
                              hipStream_t stream) {
    const float* x = (const float*)d_in[0];
    const int* eidx = (const int*)d_in[1];
    const int* batch = (const int*)d_in[2];
    const int* src = eidx;
    const int* dst = eidx + N_EDGES;
    const float* W1[3] = {(const float*)d_in[3], (const float*)d_in[9], (const float*)d_in[15]};
    const float* B1[3] = {(const float*)d_in[4], (const float*)d_in[10], (const float*)d_in[16]};
    const float* W2[3] = {(const float*)d_in[5], (const float*)d_in[11], (const float*)d_in[17]};
    const float* B2[3] = {(const float*)d_in[6], (const float*)d_in[12], (const float*)d_in[18]};
    const float* GM[3] = {(const float*)d_in[7], (const float*)d_in[13], (const float*)d_in[19]};
    const float* BT[3] = {(const float*)d_in[8], (const float*)d_in[14], (const float*)d_in[20]};
    const float* PW = (const float*)d_in[21];
    const float* PB = (const float*)d_in[22];
    float* out = (float*)d_out;

    char* ws = (char*)d_ws;
    size_t off = 0;
    auto alloc = [&](size_t bytes) -> void* {
        void* p = ws + off;
        off += (bytes + 255) & ~(size_t)255;
        return p;
    };
    float* A    = (float*)alloc((size_t)N_NODES * 64 * 4);  // h2 buffer
    float* C    = (float*)alloc((size_t)N_NODES * 64 * 4);  // agg buffer
    float* agg0 = (float*)alloc((size_t)N_NODES * 7 * 4);
    int* cnt    = (int*)alloc((size_t)N_NODES * 4);
    int* rowptr = (int*)alloc((size_t)N_NODES * 4);
    int* cursor = (int*)alloc((size_t)N_NODES * 4);
    int* bsum   = (int*)alloc(NSCAN * 4);
    int* elist  = (int*)alloc((size_t)N_EDGES * 4);
    int* gcnt   = (int*)alloc(1024 * 4);
    int* grow   = (int*)alloc(1025 * 4);
    double* acc = (double*)alloc(3 * 128 * sizeof(double));
    float* ss0    = (float*)alloc(128 * 4);
    float* ss1    = (float*)alloc(128 * 4);
    float* ss2    = (float*)alloc(128 * 4);
    float* pooled = (float*)alloc((size_t)N_GRAPHS * 64 * 4);

    hipMemsetAsync(cnt, 0, (size_t)N_NODES * 4, stream);
    hipMemsetAsync(gcnt, 0, 1024 * 4, stream);
    hipMemsetAsync(acc, 0, 3 * 128 * sizeof(double), stream);

    const int edge_grid = (N_EDGES + 255) / 256;       // 6250
    const int row_grid = (N_NODES + 255) / 256;        // 391
    const int vec_grid = (N_NODES * 16 + 255) / 256;   // 6250
    const int g7_grid = (N_NODES * 8 + 255) / 256;     // 3125

    // ---- CSR build (node-level, reused by all 3 layers; graph-level for pool) ----
    hist_kernel<<<edge_grid, 256, 0, stream>>>(dst, cnt);
    ghist_kernel<<<row_grid, 256, 0, stream>>>(batch, gcnt);
    scan_blocks<<<NSCAN, 256, 0, stream>>>(cnt, rowptr, bsum);
    scan_sums<<<1, 64, 0, stream>>>(bsum);
    scan_apply<<<row_grid, 256, 0, stream>>>(rowptr, bsum, cursor);
    gscan_kernel<<<1, 256, 0, stream>>>(gcnt, grow);
    scatter_kernel<<<edge_grid, 256, 0, stream>>>(src, dst, cursor, elist);

    // ---- layer 0 ----
    gather7<<<g7_grid, 256, 0, stream>>>(x, rowptr, cnt, elist, agg0);
    mlp_kernel<7><<<row_grid, 256, 0, stream>>>(agg0, W1[0], B1[0], W2[0], B2[0], A);
    bn_stats<<<row_grid, 256, 0, stream>>>(A, acc);
    bn_finalize<<<1, 64, 0, stream>>>(acc, GM[0], BT[0], ss0);

    // ---- layer 1 (BN+relu of layer 0 fused into gather) ----
    gather64_bn<<<vec_grid, 256, 0, stream>>>(A, ss0, rowptr, cnt, elist, C);
    mlp_kernel<64><<<row_grid, 256, 0, stream>>>(C, W1[1], B1[1], W2[1], B2[1], A);
    bn_stats<<<row_grid, 256, 0, stream>>>(A, acc + 128);
    bn_finalize<<<1, 64, 0, stream>>>(acc + 128, GM[1], BT[1], ss1);

    // ---- layer 2 ----
    gather64_bn<<<vec_grid, 256, 0, stream>>>(A, ss1, rowptr, cnt, elist, C);
    mlp_kernel<64><<<row_grid, 256, 0, stream>>>(C, W1[2], B1[2], W2[2], B2[2], A);
    bn_stats<<<row_grid, 256, 0, stream>>>(A, acc + 256);
    bn_finalize<<<1, 64, 0, stream>>>(acc + 256, GM[2], BT[2], ss2);

    // ---- pool (BN+relu fused, deterministic per-graph reduction) ----
    pool_bn<<<N_GRAPHS, 256, 0, stream>>>(A, ss2, grow, pooled);

    // ---- readout ----
    final_proj<<<N_GRAPHS / 4, 256, 0, stream>>>(pooled, PW, PB, out);
}